// Round 3
// baseline (178.583 us; speedup 1.0000x reference)
//
#include <hip/hip_runtime.h>

// Problem constants
#define B_  2
#define N_  20000
#define C_  256
#define K_  5000
#define M_  (B_ * K_)     // 10000
#define CAP_ 5376         // survivor capacity per batch
#define NBIN_ 2048
#define AST_ 264          // act LDS row stride (shorts): 16B-aligned

typedef __attribute__((ext_vector_type(8))) short bf16x8;
typedef __attribute__((ext_vector_type(4))) float f32x4;

__device__ __forceinline__ unsigned short f2bf(float x) {
  unsigned u = __float_as_uint(x);
  return (unsigned short)((u + 0x7fffu + ((u >> 16) & 1u)) >> 16);
}
__device__ __forceinline__ unsigned fkey(float f) {
  unsigned u = __float_as_uint(f);
  return (u & 0x80000000u) ? ~u : (u | 0x80000000u);
}
// monotone linear bin; only hist/compact CONSISTENCY matters (upward-closed set)
__device__ __forceinline__ int binof(float s) {
  int b = (int)(s * 2048.0f);
  return b < 0 ? 0 : (b > 2047 ? 2047 : b);
}
__device__ __forceinline__ bf16x8 as_bf(uint4 v) {
  union { uint4 u; bf16x8 b; } c; c.u = v; return c.b;
}

// ---------------------------------------------------------------------------
// K1: W f32 -> bf16 (RNE), PRE-PACKED into per-wave MFMA fragment order
// (layout symmetric for A/B operands: row/col = lane&15, k = (lane>>4)*8+j).
// Blocks 192/193: per-batch score histogram + threshold bin -> h_glob, selb.
// Blocks 194+: rnk init to K_ (moved from old k_selcomp).
__global__ __launch_bounds__(256) void k_prep(const float* __restrict__ W,
                                              const float* __restrict__ score,
                                              unsigned short* __restrict__ Whi,
                                              int* __restrict__ selb,
                                              int* __restrict__ h_glob,
                                              int* __restrict__ rnk) {
  const int u = blockIdx.x;
  const int t = threadIdx.x;
  if (u >= 192) {
    if (u >= 194) {
      const int i = (u - 194) * 256 + t;
      if (i < B_ * N_) rnk[i] = K_;
      return;
    }
    // one block per batch: full histogram + select threshold bin
    const int b = u - 192;
    __shared__ int h[NBIN_];
    __shared__ int chs[256];
    const float* s = score + b * N_;
    for (int i = t; i < NBIN_; i += 256) h[i] = 0;
    __syncthreads();
    // N_ = 20000 = 5000 float4
    for (int i = t; i < N_ / 4; i += 256) {
      const float4 v = ((const float4*)s)[i];
      atomicAdd(&h[binof(v.x)], 1);
      atomicAdd(&h[binof(v.y)], 1);
      atomicAdd(&h[binof(v.z)], 1);
      atomicAdd(&h[binof(v.w)], 1);
    }
    __syncthreads();
    int sum = 0;
#pragma unroll
    for (int j = 0; j < 8; ++j) sum += h[t * 8 + j];
    chs[t] = sum;
    __syncthreads();
    for (int off = 1; off < 256; off <<= 1) {
      int v = chs[t] + ((t + off < 256) ? chs[t + off] : 0);
      __syncthreads();
      chs[t] = v;
      __syncthreads();
    }
    const int above = (t + 1 < 256) ? chs[t + 1] : 0;
    if (above < K_ && K_ <= chs[t]) {
      int acc = above;
      for (int i = 7; i >= 0; --i) {
        const int bin = t * 8 + i;
        if (acc + h[bin] >= K_) { selb[b] = bin; break; }
        acc += h[bin];
      }
    }
    for (int i = t; i < NBIN_; i += 256) h_glob[b * NBIN_ + i] = h[i];
    return;
  }
  const int idx = u * 256 + t;  // 0..49151 = [l][w][ks][oi][lane]
  const int lane = idx & 63;
  const int oi = (idx >> 6) & 1;
  const int ks = (idx >> 7) & 7;
  const int w = (idx >> 10) & 7;
  const int l = idx >> 13;
  const int o = w * 32 + oi * 16 + (lane & 15);
  const int k0 = ks * 32 + (lane >> 4) * 8;
  const float* src = W + ((size_t)(l * C_ + o)) * C_ + k0;
  float4 w0 = *(const float4*)&src[0];
  float4 w1 = *(const float4*)&src[4];
  const float wv[8] = {w0.x, w0.y, w0.z, w0.w, w1.x, w1.y, w1.z, w1.w};
  unsigned short hs[8];
#pragma unroll
  for (int q = 0; q < 8; ++q) hs[q] = f2bf(wv[q]);
  *(uint4*)&Whi[(size_t)idx * 8] = *(const uint4*)&hs[0];
}

// ---------------------------------------------------------------------------
// K2 (new): bucket-rank + scatter, one block per batch, 1024 threads.
// rank(j) = (#keys in bins > bin_j) + (#keys in bin_j greater than key_j).
// Bins hold ~10 survivors -> ~50K within-bin compares total (vs 58M all-pairs).
// Replaces old k_selcomp + k_rank2 + k_scatter2 (and ck/nc/cnt2 buffers).
// Keys (score,idx) are unique -> ranks deterministic regardless of atomic order.
__global__ __launch_bounds__(1024) void k_rankscatter(
    const float* __restrict__ score, const int* __restrict__ selb,
    const int* __restrict__ h_glob, const float* __restrict__ box,
    int* __restrict__ keep_i, float* __restrict__ out_keep,
    int* __restrict__ rnk, float* __restrict__ boxK,
    unsigned* __restrict__ maxiou) {
  __shared__ int h[NBIN_];
  __shared__ int sfx[NBIN_];
  __shared__ int chs[1024];
  __shared__ unsigned long long sorted[CAP_];   // 43008B; total LDS 63488B
  const int b = blockIdx.x;
  const int t = threadIdx.x;
  const int selB = selb[b];
  h[t] = h_glob[b * NBIN_ + t];
  h[t + 1024] = h_glob[b * NBIN_ + t + 1024];
  __syncthreads();
  // suffix scan over 2048 bins (2 bins/thread chunks)
  chs[t] = h[2 * t] + h[2 * t + 1];
  __syncthreads();
  for (int off = 1; off < 1024; off <<= 1) {
    int v = chs[t] + ((t + off < 1024) ? chs[t + off] : 0);
    __syncthreads();
    chs[t] = v;
    __syncthreads();
  }
  const int above = (t + 1 < 1024) ? chs[t + 1] : 0;
  sfx[2 * t + 1] = above;
  sfx[2 * t] = above + h[2 * t + 1];
  __syncthreads();
  int S = sfx[selB] + h[selB];   // survivor count (bins >= selB)
  if (S > CAP_) S = CAP_;
  __syncthreads();               // all reads of h done before rezero
  h[t] = 0; h[t + 1024] = 0;     // reuse h as per-bin scatter counters
  __syncthreads();
  // compaction pass: scores -> bin-bucketed LDS (descending-bin order)
  const float* s = score + b * N_;
  for (int i4 = t; i4 < N_ / 4; i4 += 1024) {
    const float4 v = ((const float4*)s)[i4];
    const float sv[4] = {v.x, v.y, v.z, v.w};
#pragma unroll
    for (int q = 0; q < 4; ++q) {
      const int bin = binof(sv[q]);
      if (bin >= selB) {
        const int pos = sfx[bin] + atomicAdd(&h[bin], 1);
        if (pos < CAP_) {
          const int n = i4 * 4 + q;
          sorted[pos] = ((unsigned long long)fkey(sv[q]) << 32) |
                        (unsigned)(N_ - 1 - n);
        }
      }
    }
  }
  __syncthreads();
  // exact rank within bin segment + fused scatter of all outputs
  const float* bb = box + (size_t)b * 4 * N_;
  for (int p = t; p < S; p += 1024) {
    const unsigned long long k = sorted[p];
    const unsigned fk = (unsigned)(k >> 32);
    const unsigned uu = (fk & 0x80000000u) ? (fk & 0x7fffffffu) : ~fk;
    const int bin = binof(__uint_as_float(uu));
    const int start = sfx[bin];
    int end = start + h[bin];
    if (end > S) end = S;
    int c = start;
    for (int q2 = start; q2 < end; ++q2) c += (int)(sorted[q2] > k);
    if (c >= K_) continue;
    const int n = N_ - 1 - (int)(k & 0xffffffffu);
    keep_i[b * K_ + c] = n;
    out_keep[b * K_ + c] = (float)n;
    rnk[b * N_ + n] = c;
    float4 v;
    v.x = bb[n]; v.y = bb[N_ + n]; v.z = bb[2 * N_ + n]; v.w = bb[3 * N_ + n];
    ((float4*)boxK)[b * K_ + c] = v;
    maxiou[b * K_ + c] = 0u;
  }
}

// ---------------------------------------------------------------------------
// K5: iou (420 triangular units) + gather/transpose/bf16 (2504 units).
__global__ __launch_bounds__(256) void k_ioug(const float* __restrict__ boxK,
                                              unsigned* __restrict__ maxiou,
                                              const int* __restrict__ rnk,
                                              const float* __restrict__ feat,
                                              unsigned short* __restrict__ Xhi) {
  __shared__ __align__(16) char arena[16640];
  const int u = blockIdx.x;
  const int t = threadIdx.x;
  if (u < 420) {
    const int b = u / 210;
    const int p = u % 210;
    int jt = 0;
    while ((jt + 1) * (jt + 2) / 2 <= p) ++jt;
    const int it = p - jt * (jt + 1) / 2;
    float* sx0 = (float*)arena;
    float* sy0 = sx0 + 256; float* sx1 = sy0 + 256;
    float* sy1 = sx1 + 256; float* sa = sy1 + 256;
    const int gi0 = it * 256;
    const int gl = gi0 + t;
    if (gl < K_) {
      float4 v = ((const float4*)boxK)[b * K_ + gl];
      sx0[t] = v.x; sy0[t] = v.y; sx1[t] = v.z; sy1[t] = v.w;
      sa[t] = __fmul_rn(__fsub_rn(v.z, v.x), __fsub_rn(v.w, v.y));
    } else {
      sx0[t] = 1e30f; sy0[t] = 1e30f; sx1[t] = -1e30f; sy1[t] = -1e30f;
      sa[t] = 0.f;
    }
    __syncthreads();
    const int j = jt * 256 + t;
    if (j >= K_) return;
    float4 v = ((const float4*)boxK)[b * K_ + j];
    const float aj = __fmul_rn(__fsub_rn(v.z, v.x), __fsub_rn(v.w, v.y));
    float mx = 0.f;
    int lim = j - gi0;
    if (lim > 256) lim = 256;
    for (int ii = 0; ii < lim; ++ii) {
      float ltx = fmaxf(sx0[ii], v.x);
      float lty = fmaxf(sy0[ii], v.y);
      float rbx = fminf(sx1[ii], v.z);
      float rby = fminf(sy1[ii], v.w);
      float wx = fmaxf(__fsub_rn(rbx, ltx), 0.f);
      float wy = fmaxf(__fsub_rn(rby, lty), 0.f);
      float inter = __fmul_rn(wx, wy);
      if (inter > 0.f) {
        float uni = __fsub_rn(__fadd_rn(sa[ii], aj), inter);
        mx = fmaxf(mx, __fdiv_rn(inter, uni));
      }
    }
    if (mx > 0.f) atomicMax(&maxiou[b * K_ + j], __float_as_uint(mx));
  } else {
    const int v2 = u - 420;
    const int b = v2 / 1252;
    const int rem = v2 % 1252;
    const int c0 = (rem / 313) * 64;
    const int n0 = (rem % 313) * 64;
    float* T = (float*)arena;  // [64][65]
    const int nl = t & 63, wq = t >> 6;
#pragma unroll
    for (int r = 0; r < 16; ++r) {
      const int cl = r * 4 + wq;
      const int n = n0 + nl;
      T[nl * 65 + cl] =
          (n < N_) ? feat[((size_t)(b * C_ + c0 + cl)) * N_ + n] : 0.f;
    }
    __syncthreads();
    const int nn = n0 + (t >> 2);
    if (nn >= N_) return;
    const int r = rnk[b * N_ + nn];
    if (r >= K_) return;
    const int cseg = (t & 3) * 16;
    unsigned short hb[16];
#pragma unroll
    for (int i = 0; i < 16; ++i)
      hb[i] = f2bf(T[(t >> 2) * 65 + cseg + i]);
    const size_t base = (size_t)(b * K_ + r) * C_ + c0 + cseg;
    *(uint4*)&Xhi[base] = *(const uint4*)&hb[0];
    *(uint4*)&Xhi[base + 8] = *(const uint4*)&hb[8];
  }
}

// ---------------------------------------------------------------------------
// K6: all 6 MLP layers, pure-bf16 operands + f32 MFMA accumulate, activations
// resident in LDS (32 rows/block), 512 threads = 8 waves, operand-swapped
// MFMA (lane owns 4 consecutive o-features -> packed ds_write_b64 epilogue),
// then fused final 3-row GEMV + softmax + masked sum. Bit-exact (absmax 0.0).
__global__ __launch_bounds__(512, 2) void k_mlp6(
    const unsigned short* __restrict__ Whi,
    const float* __restrict__ bias, const float* __restrict__ Wf,
    const float* __restrict__ bf, const unsigned* __restrict__ maxiou,
    const unsigned short* __restrict__ Xhi,
    float* __restrict__ out_loc) {
  __shared__ __align__(16) unsigned short act_hi[32 * AST_];
  __shared__ float swf[768];
  const int t = threadIdx.x;
  const int m0 = blockIdx.x * 32;

  {
    const int r = t >> 4;
    const int cs = (t & 15) * 16;
    const size_t g = (size_t)(m0 + r) * C_ + cs;
    *(uint4*)&act_hi[r * AST_ + cs] = *(const uint4*)&Xhi[g];
    *(uint4*)&act_hi[r * AST_ + cs + 8] = *(const uint4*)&Xhi[g + 8];
  }
  for (int i = t; i < 768; i += 512) swf[i] = Wf[i];
  __syncthreads();

  const int lane = t & 63;
  const int w = t >> 6;            // wave id -> o base w*32
  const int quad = lane >> 4, l15 = lane & 15;

  for (int l = 0; l < 6; ++l) {
    const size_t wbase = (size_t)(l * 8 + w) * 8192 + (size_t)lane * 8;
    f32x4 acc[2][2];  // [oi][mi]
#pragma unroll
    for (int oi = 0; oi < 2; ++oi)
#pragma unroll
      for (int mi = 0; mi < 2; ++mi) acc[oi][mi] = (f32x4)0.f;
    uint4 nwh[2];
#pragma unroll
    for (int oi = 0; oi < 2; ++oi)
      nwh[oi] = *(const uint4*)&Whi[wbase + oi * 512];
#pragma unroll
    for (int ks = 0; ks < 8; ++ks) {
      bf16x8 wh[2];
#pragma unroll
      for (int oi = 0; oi < 2; ++oi) wh[oi] = as_bf(nwh[oi]);
      if (ks < 7) {
        const size_t nb = wbase + (size_t)(ks + 1) * 1024;
#pragma unroll
        for (int oi = 0; oi < 2; ++oi)
          nwh[oi] = *(const uint4*)&Whi[nb + oi * 512];
      }
      bf16x8 Ah[2];
#pragma unroll
      for (int mi = 0; mi < 2; ++mi)
        Ah[mi] = *(const bf16x8*)&act_hi[(mi * 16 + l15) * AST_ + ks * 32 + quad * 8];
#pragma unroll
      for (int mi = 0; mi < 2; ++mi)
#pragma unroll
        for (int oi = 0; oi < 2; ++oi)
          acc[oi][mi] = __builtin_amdgcn_mfma_f32_16x16x32_bf16(wh[oi], Ah[mi], acc[oi][mi], 0, 0, 0);
    }
    __syncthreads();
    const int o0 = w * 32 + quad * 4;
#pragma unroll
    for (int oi = 0; oi < 2; ++oi) {
      const float4 bb = *(const float4*)&bias[l * C_ + o0 + oi * 16];
#pragma unroll
      for (int mi = 0; mi < 2; ++mi) {
        float y0 = acc[oi][mi][0] + bb.x; y0 = fmaxf(y0, 0.2f * y0);
        float y1 = acc[oi][mi][1] + bb.y; y1 = fmaxf(y1, 0.2f * y1);
        float y2 = acc[oi][mi][2] + bb.z; y2 = fmaxf(y2, 0.2f * y2);
        float y3 = acc[oi][mi][3] + bb.w; y3 = fmaxf(y3, 0.2f * y3);
        uint2 pk;
        pk.x = (unsigned)f2bf(y0) | ((unsigned)f2bf(y1) << 16);
        pk.y = (unsigned)f2bf(y2) | ((unsigned)f2bf(y3) << 16);
        *(uint2*)&act_hi[(mi * 16 + l15) * AST_ + o0 + oi * 16] = pk;
      }
    }
    __syncthreads();
  }

  const int r = t >> 4;
  const int part = t & 15;
  const int m = m0 + r;
  float a0 = 0.f, a1 = 0.f, a2 = 0.f;
  for (int c = part * 16; c < part * 16 + 16; c += 2) {
    const unsigned hv = *(const unsigned*)&act_hi[r * AST_ + c];
    const float x0 = __uint_as_float((hv & 0xffffu) << 16);
    const float x1 = __uint_as_float(hv & 0xffff0000u);
    a0 += swf[c] * x0 + swf[c + 1] * x1;
    a1 += swf[256 + c] * x0 + swf[256 + c + 1] * x1;
    a2 += swf[512 + c] * x0 + swf[512 + c + 1] * x1;
  }
#pragma unroll
  for (int off = 1; off < 16; off <<= 1) {
    a0 += __shfl_xor(a0, off);
    a1 += __shfl_xor(a1, off);
    a2 += __shfl_xor(a2, off);
  }
  if (part == 0 && m < M_) {
    a0 += bf[0]; a1 += bf[1]; a2 += bf[2];
    const float mxv = fmaxf(a0, fmaxf(a1, a2));
    const float e0 = expf(a0 - mxv);
    const float e1 = expf(a1 - mxv);
    const float e2 = expf(a2 - mxv);
    const float inv = 1.f / (e0 + e1 + e2);
    const float miou = __uint_as_float(maxiou[m]);
    float loc = 0.f;
    if (miou < 0.4f) loc += e0;
    if (miou < 0.6f) loc += e1;
    if (miou < 0.8f) loc += e2;
    out_loc[m] = loc * inv;
  }
}

// ---------------------------------------------------------------------------
extern "C" void kernel_launch(void* const* d_in, const int* in_sizes, int n_in,
                              void* d_out, int out_size, void* d_ws, size_t ws_size,
                              hipStream_t stream) {
  const float* box   = (const float*)d_in[0];
  const float* score = (const float*)d_in[1];
  const float* feat  = (const float*)d_in[2];
  const float* W     = (const float*)d_in[3];
  const float* bias  = (const float*)d_in[4];
  const float* Wf    = (const float*)d_in[5];
  const float* bf    = (const float*)d_in[6];

  float* out = (float*)d_out;
  float* out_loc  = out;
  float* out_keep = out + M_;

  char* ws = (char*)d_ws;
  int*            keep_i = (int*)(ws + 0);
  float*          boxK   = (float*)(ws + 40960);
  unsigned*       maxiou = (unsigned*)(ws + 201216);
  unsigned short* Whi    = (unsigned short*)(ws + 241664);
  unsigned short* XtA_hi = (unsigned short*)(ws + 1814528);
  int*                rnk    = (int*)(ws + 12169216);
  int*                h_glob = (int*)(ws + 12329216);
  int*                selb   = (int*)(ws + 12345600);

  k_prep<<<351, 256, 0, stream>>>(W, score, Whi, selb, h_glob, rnk);
  k_rankscatter<<<B_, 1024, 0, stream>>>(score, selb, h_glob, box, keep_i,
                                         out_keep, rnk, boxK, maxiou);
  k_ioug<<<2924, 256, 0, stream>>>(boxK, maxiou, rnk, feat, XtA_hi);
  k_mlp6<<<313, 512, 0, stream>>>(Whi, bias, Wf, bf, maxiou, XtA_hi, out_loc);
}

// Round 4
// 157.747 us; speedup vs baseline: 1.1321x; 1.1321x over previous
//
#include <hip/hip_runtime.h>

// Problem constants
#define B_  2
#define N_  20000
#define C_  256
#define K_  5000
#define M_  (B_ * K_)     // 10000
#define CAP_ 5376         // survivor capacity per batch (= 21*256)
#define NBIN_ 2048
#define AST_ 264          // act LDS row stride (shorts): 16B-aligned
#define HPB_ 8            // histogram partial blocks per batch

typedef __attribute__((ext_vector_type(8))) short bf16x8;
typedef __attribute__((ext_vector_type(4))) float f32x4;

__device__ __forceinline__ unsigned short f2bf(float x) {
  unsigned u = __float_as_uint(x);
  return (unsigned short)((u + 0x7fffu + ((u >> 16) & 1u)) >> 16);
}
__device__ __forceinline__ unsigned fkey(float f) {
  unsigned u = __float_as_uint(f);
  return (u & 0x80000000u) ? ~u : (u | 0x80000000u);
}
// monotone linear bin; only hist/compact CONSISTENCY matters (upward-closed set)
__device__ __forceinline__ int binof(float s) {
  int b = (int)(s * 2048.0f);
  return b < 0 ? 0 : (b > 2047 ? 2047 : b);
}
__device__ __forceinline__ bf16x8 as_bf(uint4 v) {
  union { uint4 u; bf16x8 b; } c; c.u = v; return c.b;
}

// ---------------------------------------------------------------------------
// Redundant per-block scan preamble (256 threads): sum HPB_ histogram partials
// -> h[2048]; suffix-scan -> sfx[bin] = #keys in bins > bin; select threshold
// bin -> *selp. ~64KB L2 reads + ~700cy of scan; cheap enough to redo per
// block, which removes all cross-block serialization of the rank pipeline.
__device__ __forceinline__ void rank_preamble(const int* __restrict__ hp,
                                              const int t, int* h, int* sfx,
                                              int* chs, int* selp) {
  int hb[8];
  {
    int4 a0 = {0, 0, 0, 0}, a1 = {0, 0, 0, 0};
#pragma unroll
    for (int p = 0; p < HPB_; ++p) {
      const int4 v0 = *(const int4*)&hp[p * NBIN_ + t * 8];
      const int4 v1 = *(const int4*)&hp[p * NBIN_ + t * 8 + 4];
      a0.x += v0.x; a0.y += v0.y; a0.z += v0.z; a0.w += v0.w;
      a1.x += v1.x; a1.y += v1.y; a1.z += v1.z; a1.w += v1.w;
    }
    hb[0] = a0.x; hb[1] = a0.y; hb[2] = a0.z; hb[3] = a0.w;
    hb[4] = a1.x; hb[5] = a1.y; hb[6] = a1.z; hb[7] = a1.w;
    *(int4*)&h[t * 8] = a0;
    *(int4*)&h[t * 8 + 4] = a1;
  }
  chs[t] = hb[0] + hb[1] + hb[2] + hb[3] + hb[4] + hb[5] + hb[6] + hb[7];
  __syncthreads();
  for (int off = 1; off < 256; off <<= 1) {
    int v = chs[t] + ((t + off < 256) ? chs[t + off] : 0);
    __syncthreads();
    chs[t] = v;
    __syncthreads();
  }
  const int above = (t + 1 < 256) ? chs[t + 1] : 0;
  int run = above;
  sfx[t * 8 + 7] = run;
#pragma unroll
  for (int i = 7; i > 0; --i) { run += hb[i]; sfx[t * 8 + i - 1] = run; }
  if (above < K_ && K_ <= chs[t]) {
    int acc = above;
#pragma unroll
    for (int i = 7; i >= 0; --i) {
      if (acc + hb[i] >= K_) { *selp = t * 8 + i; break; }
      acc += hb[i];
    }
  }
  __syncthreads();
}

// ---------------------------------------------------------------------------
// K1: W f32 -> bf16 (RNE), PRE-PACKED into per-wave MFMA fragment order
// (layout symmetric for A/B operands: row/col = lane&15, k = (lane>>4)*8+j).
// Blocks [192,349): rnk init. Blocks [349,365): DISTRIBUTED histogram (8
// blocks/batch, each writes a full 2048-bin partial row -> no zero/atomics).
// Block 365: zero gcnt.  All phases >=16-way parallel (R3's 2-block
// histogram tail was ~6-7us of near-idle GPU).
__global__ __launch_bounds__(256) void k_prep(const float* __restrict__ W,
                                              const float* __restrict__ score,
                                              unsigned short* __restrict__ Whi,
                                              int* __restrict__ rnk,
                                              int* __restrict__ hpart,
                                              int* __restrict__ gcnt) {
  const int u = blockIdx.x;
  const int t = threadIdx.x;
  if (u >= 192) {
    if (u < 349) {
      const int i = (u - 192) * 256 + t;
      if (i < B_ * N_) rnk[i] = K_;
      return;
    }
    if (u < 365) {
      const int hb = u - 349;
      const int b = hb >> 3, seg = hb & 7;   // 8 blocks/batch, 625 f4 each
      __shared__ int lh[NBIN_];
      for (int i = t; i < NBIN_; i += 256) lh[i] = 0;
      __syncthreads();
      const float4* s4 = (const float4*)(score + b * N_);
      for (int idx = t; idx < 625; idx += 256) {
        const float4 v = s4[seg * 625 + idx];
        atomicAdd(&lh[binof(v.x)], 1);
        atomicAdd(&lh[binof(v.y)], 1);
        atomicAdd(&lh[binof(v.z)], 1);
        atomicAdd(&lh[binof(v.w)], 1);
      }
      __syncthreads();
      int* dst = hpart + (size_t)hb * NBIN_;
      for (int i = t; i < NBIN_; i += 256) dst[i] = lh[i];
      return;
    }
    // u == 365: zero per-bin global scatter counters
    for (int i = t; i < B_ * NBIN_; i += 256) gcnt[i] = 0;
    return;
  }
  const int idx = u * 256 + t;  // 0..49151 = [l][w][ks][oi][lane]
  const int lane = idx & 63;
  const int oi = (idx >> 6) & 1;
  const int ks = (idx >> 7) & 7;
  const int w = (idx >> 10) & 7;
  const int l = idx >> 13;
  const int o = w * 32 + oi * 16 + (lane & 15);
  const int k0 = ks * 32 + (lane >> 4) * 8;
  const float* src = W + ((size_t)(l * C_ + o)) * C_ + k0;
  float4 w0 = *(const float4*)&src[0];
  float4 w1 = *(const float4*)&src[4];
  const float wv[8] = {w0.x, w0.y, w0.z, w0.w, w1.x, w1.y, w1.z, w1.w};
  unsigned short hs[8];
#pragma unroll
  for (int q = 0; q < 8; ++q) hs[q] = f2bf(wv[q]);
  *(uint4*)&Whi[(size_t)idx * 8] = *(const uint4*)&hs[0];
}

// ---------------------------------------------------------------------------
// K2: distributed compact. 20 blocks/batch; each: redundant scan preamble,
// then bucket its 1000-score slice into global bin-sorted order via gcnt
// device atomics. Keys unique -> intra-bin order irrelevant to final ranks.
__global__ __launch_bounds__(256) void k_compact(const float* __restrict__ score,
                                                 const int* __restrict__ hpart,
                                                 int* __restrict__ gcnt,
                                                 unsigned long long* __restrict__ sorted_g) {
  __shared__ int h[NBIN_], sfx[NBIN_], chs[256];
  __shared__ int sel_s;
  const int b = blockIdx.y;
  const int t = threadIdx.x;
  rank_preamble(hpart + (size_t)b * HPB_ * NBIN_, t, h, sfx, chs, &sel_s);
  const int selB = sel_s;
  if (t >= 250) return;
  const int i4 = blockIdx.x * 250 + t;   // 20*250 = 5000 f4 = N_
  const float4 v = ((const float4*)(score + b * N_))[i4];
  const float sv[4] = {v.x, v.y, v.z, v.w};
#pragma unroll
  for (int q = 0; q < 4; ++q) {
    const int bin = binof(sv[q]);
    if (bin >= selB) {
      const int pos = sfx[bin] + atomicAdd(&gcnt[b * NBIN_ + bin], 1);
      if (pos < CAP_) {
        const int n = i4 * 4 + q;
        sorted_g[(size_t)b * CAP_ + pos] =
            ((unsigned long long)fkey(sv[q]) << 32) | (unsigned)(N_ - 1 - n);
      }
    }
  }
}

// ---------------------------------------------------------------------------
// K3: distributed rank + scatter. 21 blocks/batch x 256 (covers CAP_); each
// thread ranks one survivor against its ~10-entry bin segment (global,
// L2-hot) and scatters keep/out_keep/rnk/boxK/maxiou. rank(j) = sfx[bin_j] +
// (#keys in bin_j greater than key_j); deterministic (keys unique).
__global__ __launch_bounds__(256) void k_rank(const int* __restrict__ hpart,
                                              const unsigned long long* __restrict__ sorted_g,
                                              const float* __restrict__ box,
                                              int* __restrict__ keep_i,
                                              float* __restrict__ out_keep,
                                              int* __restrict__ rnk,
                                              float* __restrict__ boxK,
                                              unsigned* __restrict__ maxiou) {
  __shared__ int h[NBIN_], sfx[NBIN_], chs[256];
  __shared__ int sel_s;
  const int b = blockIdx.y;
  const int t = threadIdx.x;
  rank_preamble(hpart + (size_t)b * HPB_ * NBIN_, t, h, sfx, chs, &sel_s);
  const int selB = sel_s;
  int S = sfx[selB] + h[selB];
  if (S > CAP_) S = CAP_;
  const int p = blockIdx.x * 256 + t;
  if (p >= S) return;
  const unsigned long long* sb = sorted_g + (size_t)b * CAP_;
  const unsigned long long k = sb[p];
  const unsigned fk = (unsigned)(k >> 32);
  const unsigned uu = (fk & 0x80000000u) ? (fk & 0x7fffffffu) : ~fk;
  const int bin = binof(__uint_as_float(uu));
  const int start = sfx[bin];
  int end = start + h[bin];
  if (end > S) end = S;
  int c = start;
  for (int q2 = start; q2 < end; ++q2) c += (int)(sb[q2] > k);
  if (c >= K_) return;
  const int n = N_ - 1 - (int)(k & 0xffffffffu);
  keep_i[b * K_ + c] = n;
  out_keep[b * K_ + c] = (float)n;
  rnk[b * N_ + n] = c;
  const float* bb = box + (size_t)b * 4 * N_;
  float4 v;
  v.x = bb[n]; v.y = bb[N_ + n]; v.z = bb[2 * N_ + n]; v.w = bb[3 * N_ + n];
  ((float4*)boxK)[b * K_ + c] = v;
  maxiou[b * K_ + c] = 0u;
}

// ---------------------------------------------------------------------------
// K5: iou (420 triangular units) + gather/transpose/bf16 (2504 units).
__global__ __launch_bounds__(256) void k_ioug(const float* __restrict__ boxK,
                                              unsigned* __restrict__ maxiou,
                                              const int* __restrict__ rnk,
                                              const float* __restrict__ feat,
                                              unsigned short* __restrict__ Xhi) {
  __shared__ __align__(16) char arena[16640];
  const int u = blockIdx.x;
  const int t = threadIdx.x;
  if (u < 420) {
    const int b = u / 210;
    const int p = u % 210;
    int jt = 0;
    while ((jt + 1) * (jt + 2) / 2 <= p) ++jt;
    const int it = p - jt * (jt + 1) / 2;
    float* sx0 = (float*)arena;
    float* sy0 = sx0 + 256; float* sx1 = sy0 + 256;
    float* sy1 = sx1 + 256; float* sa = sy1 + 256;
    const int gi0 = it * 256;
    const int gl = gi0 + t;
    if (gl < K_) {
      float4 v = ((const float4*)boxK)[b * K_ + gl];
      sx0[t] = v.x; sy0[t] = v.y; sx1[t] = v.z; sy1[t] = v.w;
      sa[t] = __fmul_rn(__fsub_rn(v.z, v.x), __fsub_rn(v.w, v.y));
    } else {
      sx0[t] = 1e30f; sy0[t] = 1e30f; sx1[t] = -1e30f; sy1[t] = -1e30f;
      sa[t] = 0.f;
    }
    __syncthreads();
    const int j = jt * 256 + t;
    if (j >= K_) return;
    float4 v = ((const float4*)boxK)[b * K_ + j];
    const float aj = __fmul_rn(__fsub_rn(v.z, v.x), __fsub_rn(v.w, v.y));
    float mx = 0.f;
    int lim = j - gi0;
    if (lim > 256) lim = 256;
    for (int ii = 0; ii < lim; ++ii) {
      float ltx = fmaxf(sx0[ii], v.x);
      float lty = fmaxf(sy0[ii], v.y);
      float rbx = fminf(sx1[ii], v.z);
      float rby = fminf(sy1[ii], v.w);
      float wx = fmaxf(__fsub_rn(rbx, ltx), 0.f);
      float wy = fmaxf(__fsub_rn(rby, lty), 0.f);
      float inter = __fmul_rn(wx, wy);
      if (inter > 0.f) {
        float uni = __fsub_rn(__fadd_rn(sa[ii], aj), inter);
        mx = fmaxf(mx, __fdiv_rn(inter, uni));
      }
    }
    if (mx > 0.f) atomicMax(&maxiou[b * K_ + j], __float_as_uint(mx));
  } else {
    const int v2 = u - 420;
    const int b = v2 / 1252;
    const int rem = v2 % 1252;
    const int c0 = (rem / 313) * 64;
    const int n0 = (rem % 313) * 64;
    float* T = (float*)arena;  // [64][65]
    const int nl = t & 63, wq = t >> 6;
#pragma unroll
    for (int r = 0; r < 16; ++r) {
      const int cl = r * 4 + wq;
      const int n = n0 + nl;
      T[nl * 65 + cl] =
          (n < N_) ? feat[((size_t)(b * C_ + c0 + cl)) * N_ + n] : 0.f;
    }
    __syncthreads();
    const int nn = n0 + (t >> 2);
    if (nn >= N_) return;
    const int r = rnk[b * N_ + nn];
    if (r >= K_) return;
    const int cseg = (t & 3) * 16;
    unsigned short hb[16];
#pragma unroll
    for (int i = 0; i < 16; ++i)
      hb[i] = f2bf(T[(t >> 2) * 65 + cseg + i]);
    const size_t base = (size_t)(b * K_ + r) * C_ + c0 + cseg;
    *(uint4*)&Xhi[base] = *(const uint4*)&hb[0];
    *(uint4*)&Xhi[base + 8] = *(const uint4*)&hb[8];
  }
}

// ---------------------------------------------------------------------------
// K6: all 6 MLP layers, pure-bf16 operands + f32 MFMA accumulate, activations
// resident in LDS (32 rows/block), 512 threads = 8 waves, operand-swapped
// MFMA (lane owns 4 consecutive o-features -> packed ds_write_b64 epilogue),
// then fused final 3-row GEMV + softmax + masked sum. Bit-exact (absmax 0.0).
__global__ __launch_bounds__(512, 2) void k_mlp6(
    const unsigned short* __restrict__ Whi,
    const float* __restrict__ bias, const float* __restrict__ Wf,
    const float* __restrict__ bf, const unsigned* __restrict__ maxiou,
    const unsigned short* __restrict__ Xhi,
    float* __restrict__ out_loc) {
  __shared__ __align__(16) unsigned short act_hi[32 * AST_];
  __shared__ float swf[768];
  const int t = threadIdx.x;
  const int m0 = blockIdx.x * 32;

  {
    const int r = t >> 4;
    const int cs = (t & 15) * 16;
    const size_t g = (size_t)(m0 + r) * C_ + cs;
    *(uint4*)&act_hi[r * AST_ + cs] = *(const uint4*)&Xhi[g];
    *(uint4*)&act_hi[r * AST_ + cs + 8] = *(const uint4*)&Xhi[g + 8];
  }
  for (int i = t; i < 768; i += 512) swf[i] = Wf[i];
  __syncthreads();

  const int lane = t & 63;
  const int w = t >> 6;            // wave id -> o base w*32
  const int quad = lane >> 4, l15 = lane & 15;

  for (int l = 0; l < 6; ++l) {
    const size_t wbase = (size_t)(l * 8 + w) * 8192 + (size_t)lane * 8;
    f32x4 acc[2][2];  // [oi][mi]
#pragma unroll
    for (int oi = 0; oi < 2; ++oi)
#pragma unroll
      for (int mi = 0; mi < 2; ++mi) acc[oi][mi] = (f32x4)0.f;
    uint4 nwh[2];
#pragma unroll
    for (int oi = 0; oi < 2; ++oi)
      nwh[oi] = *(const uint4*)&Whi[wbase + oi * 512];
#pragma unroll
    for (int ks = 0; ks < 8; ++ks) {
      bf16x8 wh[2];
#pragma unroll
      for (int oi = 0; oi < 2; ++oi) wh[oi] = as_bf(nwh[oi]);
      if (ks < 7) {
        const size_t nb = wbase + (size_t)(ks + 1) * 1024;
#pragma unroll
        for (int oi = 0; oi < 2; ++oi)
          nwh[oi] = *(const uint4*)&Whi[nb + oi * 512];
      }
      bf16x8 Ah[2];
#pragma unroll
      for (int mi = 0; mi < 2; ++mi)
        Ah[mi] = *(const bf16x8*)&act_hi[(mi * 16 + l15) * AST_ + ks * 32 + quad * 8];
#pragma unroll
      for (int mi = 0; mi < 2; ++mi)
#pragma unroll
        for (int oi = 0; oi < 2; ++oi)
          acc[oi][mi] = __builtin_amdgcn_mfma_f32_16x16x32_bf16(wh[oi], Ah[mi], acc[oi][mi], 0, 0, 0);
    }
    __syncthreads();
    const int o0 = w * 32 + quad * 4;
#pragma unroll
    for (int oi = 0; oi < 2; ++oi) {
      const float4 bb = *(const float4*)&bias[l * C_ + o0 + oi * 16];
#pragma unroll
      for (int mi = 0; mi < 2; ++mi) {
        float y0 = acc[oi][mi][0] + bb.x; y0 = fmaxf(y0, 0.2f * y0);
        float y1 = acc[oi][mi][1] + bb.y; y1 = fmaxf(y1, 0.2f * y1);
        float y2 = acc[oi][mi][2] + bb.z; y2 = fmaxf(y2, 0.2f * y2);
        float y3 = acc[oi][mi][3] + bb.w; y3 = fmaxf(y3, 0.2f * y3);
        uint2 pk;
        pk.x = (unsigned)f2bf(y0) | ((unsigned)f2bf(y1) << 16);
        pk.y = (unsigned)f2bf(y2) | ((unsigned)f2bf(y3) << 16);
        *(uint2*)&act_hi[(mi * 16 + l15) * AST_ + o0 + oi * 16] = pk;
      }
    }
    __syncthreads();
  }

  const int r = t >> 4;
  const int part = t & 15;
  const int m = m0 + r;
  float a0 = 0.f, a1 = 0.f, a2 = 0.f;
  for (int c = part * 16; c < part * 16 + 16; c += 2) {
    const unsigned hv = *(const unsigned*)&act_hi[r * AST_ + c];
    const float x0 = __uint_as_float((hv & 0xffffu) << 16);
    const float x1 = __uint_as_float(hv & 0xffff0000u);
    a0 += swf[c] * x0 + swf[c + 1] * x1;
    a1 += swf[256 + c] * x0 + swf[256 + c + 1] * x1;
    a2 += swf[512 + c] * x0 + swf[512 + c + 1] * x1;
  }
#pragma unroll
  for (int off = 1; off < 16; off <<= 1) {
    a0 += __shfl_xor(a0, off);
    a1 += __shfl_xor(a1, off);
    a2 += __shfl_xor(a2, off);
  }
  if (part == 0 && m < M_) {
    a0 += bf[0]; a1 += bf[1]; a2 += bf[2];
    const float mxv = fmaxf(a0, fmaxf(a1, a2));
    const float e0 = expf(a0 - mxv);
    const float e1 = expf(a1 - mxv);
    const float e2 = expf(a2 - mxv);
    const float inv = 1.f / (e0 + e1 + e2);
    const float miou = __uint_as_float(maxiou[m]);
    float loc = 0.f;
    if (miou < 0.4f) loc += e0;
    if (miou < 0.6f) loc += e1;
    if (miou < 0.8f) loc += e2;
    out_loc[m] = loc * inv;
  }
}

// ---------------------------------------------------------------------------
extern "C" void kernel_launch(void* const* d_in, const int* in_sizes, int n_in,
                              void* d_out, int out_size, void* d_ws, size_t ws_size,
                              hipStream_t stream) {
  const float* box   = (const float*)d_in[0];
  const float* score = (const float*)d_in[1];
  const float* feat  = (const float*)d_in[2];
  const float* W     = (const float*)d_in[3];
  const float* bias  = (const float*)d_in[4];
  const float* Wf    = (const float*)d_in[5];
  const float* bf    = (const float*)d_in[6];

  float* out = (float*)d_out;
  float* out_loc  = out;
  float* out_keep = out + M_;

  char* ws = (char*)d_ws;
  int*            keep_i = (int*)(ws + 0);
  float*          boxK   = (float*)(ws + 40960);
  unsigned*       maxiou = (unsigned*)(ws + 201216);
  unsigned short* Whi    = (unsigned short*)(ws + 241664);
  unsigned short* XtA_hi = (unsigned short*)(ws + 1814528);
  int*                rnk    = (int*)(ws + 12169216);
  int*                hpart  = (int*)(ws + 12329216);   // 16*2048*4 = 131072
  int*                gcnt   = (int*)(ws + 12460288);   // 2*2048*4  = 16384
  unsigned long long* sorted_g = (unsigned long long*)(ws + 12476672); // 86016

  k_prep<<<366, 256, 0, stream>>>(W, score, Whi, rnk, hpart, gcnt);
  k_compact<<<dim3(20, B_), 256, 0, stream>>>(score, hpart, gcnt, sorted_g);
  k_rank<<<dim3(21, B_), 256, 0, stream>>>(hpart, sorted_g, box, keep_i,
                                           out_keep, rnk, boxK, maxiou);
  k_ioug<<<2924, 256, 0, stream>>>(boxK, maxiou, rnk, feat, XtA_hi);
  k_mlp6<<<313, 512, 0, stream>>>(Whi, bias, Wf, bf, maxiou, XtA_hi, out_loc);
}